// Round 12
// baseline (2188.103 us; speedup 1.0000x reference)
//
#include <hip/hip_runtime.h>
#include <hip/hip_bf16.h>
#include <float.h>

typedef unsigned long long u64;

// ---------- exact-rounding helpers (match numpy fp32, no FMA contraction) ----------
static __device__ __forceinline__ float d2_rn(float ax, float ay, float az,
                                              float bx, float by, float bz) {
  float dx = __fsub_rn(ax, bx), dy = __fsub_rn(ay, by), dz = __fsub_rn(az, bz);
  return __fadd_rn(__fadd_rn(__fmul_rn(dx, dx), __fmul_rn(dy, dy)), __fmul_rn(dz, dz));
}

// ---------------- DPP primitives ----------------
template<int CTRL>
static __device__ __forceinline__ float dpp_f32(float x) {
  return __int_as_float(__builtin_amdgcn_update_dpp(0, __float_as_int(x), CTRL, 0xF, 0xF, true));
}

template<int CTRL>
static __device__ __forceinline__ int dpp_min_i32(int x) {
  int b = __builtin_amdgcn_update_dpp(0x7fffffff, x, CTRL, 0xF, 0xF, false);
  return x < b ? x : b;
}

// u64 cross-lane move (two 32-bit halves); bound_ctrl=1 -> invalid lanes read 0 (= -inf key)
template<int CTRL>
static __device__ __forceinline__ u64 dpp_u64(u64 x) {
  unsigned lo = (unsigned)__builtin_amdgcn_update_dpp(0, (int)(unsigned)x, CTRL, 0xF, 0xF, true);
  unsigned hi = (unsigned)__builtin_amdgcn_update_dpp(0, (int)(unsigned)(x >> 32), CTRL, 0xF, 0xF, true);
  return ((u64)hi << 32) | lo;
}

// merge two descending top-2 u64 lists (proven rounds 2-9)
static __device__ __forceinline__ void merge2(u64& a1, u64& a2, u64 b1, u64 b2) {
  bool agt = a1 > b1;
  u64 m1 = agt ? a1 : b1;
  u64 lo = agt ? b1 : a1;
  u64 cs = agt ? a2 : b2;
  a1 = m1;
  a2 = lo > cs ? lo : cs;
}

template<int CTRL>
static __device__ __forceinline__ void merge_dpp(u64& a1, u64& a2) {
  u64 b1 = dpp_u64<CTRL>(a1);
  u64 b2 = dpp_u64<CTRL>(a2);
  merge2(a1, a2, b1, b2);
}

// 16-lane u64 top-2 (patterns stay within the 16-lane row; lanes 0-15 all uniform after)
static __device__ __forceinline__ void pool16_top2(u64& a1, u64& a2) {
  merge_dpp<0xB1>(a1, a2);   // xor 1
  merge_dpp<0x4E>(a1, a2);   // xor 2
  merge_dpp<0x141>(a1, a2);  // row_half_mirror: xor-7 within 8 (valid: 4-uniform)
  merge_dpp<0x140>(a1, a2);  // row_mirror: 16-uniform
}

static __device__ __forceinline__ u64 bcast64(u64 x) {
  unsigned lo = (unsigned)__builtin_amdgcn_readfirstlane((int)(unsigned)x);
  unsigned hi = (unsigned)__builtin_amdgcn_readfirstlane((int)(x >> 32));
  return ((u64)hi << 32) | lo;
}

// ---- value-only wave top-2 + index recovery (round-11 back end, kept) ----
template<int CTRL>
static __device__ __forceinline__ void top2_step(float& v1, float& v2) {
  float b1 = dpp_f32<CTRL>(v1);
  float b2 = dpp_f32<CTRL>(v2);
  float m1 = fmaxf(v1, b1);
  float lo = fminf(v1, b1);
  v2 = fmaxf(lo, fmaxf(v2, b2));
  v1 = m1;
}

static __device__ __forceinline__ void wave_top2_vals(float& v1, float& v2) {
  top2_step<0xB1>(v1, v2);
  top2_step<0x4E>(v1, v2);
  top2_step<0x141>(v1, v2);
  top2_step<0x140>(v1, v2);
  top2_step<0x142>(v1, v2);
  top2_step<0x143>(v1, v2);  // lane 63 = full wave
}

static __device__ __forceinline__ int wave_min_idx(int c) {
  c = dpp_min_i32<0xB1>(c);  c = dpp_min_i32<0x4E>(c);
  c = dpp_min_i32<0x141>(c); c = dpp_min_i32<0x140>(c);
  c = dpp_min_i32<0x142>(c); c = dpp_min_i32<0x143>(c);
  return __builtin_amdgcn_readlane(c, 63);
}

static __device__ __forceinline__ float readlane_f(float x, int l) {
  return __int_as_float(__builtin_amdgcn_readlane(__float_as_int(x), l));
}

static __device__ __forceinline__ void wave_recover_idx(float lv1, int li1, float lv2, int li2,
                                                        float s1, float s2, int lane,
                                                        int& i1g, int& i2g) {
  u64 b1 = __ballot(lv1 == s1);
  int lw;
  if (__popcll(b1) == 1) {
    lw = __ffsll(b1) - 1;
    i1g = __builtin_amdgcn_readlane(li1, lw);
  } else {
    i1g = wave_min_idx(lv1 == s1 ? li1 : 0x7fffffff);
    lw = __ffsll(__ballot(lv1 == s1 && li1 == i1g)) - 1;
  }
  float wlv = (lane == lw) ? lv2 : lv1;
  int   wli = (lane == lw) ? li2 : li1;
  u64 b2 = __ballot(wlv == s2);
  if (__popcll(b2) == 1) {
    i2g = __builtin_amdgcn_readlane(wli, __ffsll(b2) - 1);
  } else {
    i2g = wave_min_idx(wlv == s2 ? wli : 0x7fffffff);
  }
}

#define FPS_UPD(PP)                                                                    \
  { _Pragma("unroll")                                                                  \
    for (int k = 0; k < NPT; ++k) {                                                    \
      float m = md[k];                                                                 \
      _Pragma("unroll")                                                                \
      for (int mm = 0; mm < (PP); ++mm)                                                \
        m = fminf(m, d2_rn(px[k], py[k], pz[k], cx[mm], cy[mm], cz[mm]));              \
      md[k] = m; int j = tid + k * T;                                                  \
      if (m > v2) { if (m > v1) { v2=v1; i2=i1; v1=m; i1=j; } else { v2=m; i2=j; } }   \
    } }

// ---------------- FPS: u64-key pool, accept up to 4/round (round-3 cap semantics) ----------------
template<int N, int M, int NPT, int T>
static __device__ void fps_body(const float* __restrict__ P, float* __restrict__ O,
                                char* smem) {
  constexpr int W = T / 64;
  static_assert(N == T * NPT, "layout");
  float4* pq = (float4*)smem;            // [N] interleaved coords (x,y,z,0)
  uint4* slots = (uint4*)(pq + N);       // [2][W]: (v1,i1,v2,i2)
  const int tid = threadIdx.x;
  const int lane = tid & 63, wv = tid >> 6;

  for (int j = tid; j < N; j += T)
    pq[j] = make_float4(P[3 * j], P[3 * j + 1], P[3 * j + 2], 0.f);
  __syncthreads();

  const float4 c0 = pq[0];
  if (tid == 0) { O[0] = c0.x; O[1] = c0.y; O[2] = c0.z; }

  float md[NPT], px[NPT], py[NPT], pz[NPT];
  float v1 = -1.f, v2 = -1.f; int i1 = 0, i2 = 0;
  #pragma unroll
  for (int k = 0; k < NPT; ++k) {
    int j = tid + k * T;  // ascending j -> strict '>' keeps first index on ties
    float4 p = pq[j];
    px[k] = p.x; py[k] = p.y; pz[k] = p.z;
    float m = d2_rn(p.x, p.y, p.z, c0.x, c0.y, c0.z);
    md[k] = m;
    if (m > v2) { if (m > v1) { v2=v1; i2=i1; v1=m; i1=j; } else { v2=m; i2=j; } }
  }

  {
    float r1 = v1, r2 = v2;
    wave_top2_vals(r1, r2);
    float s1 = readlane_f(r1, 63), s2 = readlane_f(r2, 63);
    int i1g, i2g;
    wave_recover_idx(v1, i1, v2, i2, s1, s2, lane, i1g, i2g);
    if (lane == 0)
      slots[wv] = make_uint4(__float_as_uint(s1), (unsigned)i1g,
                             __float_as_uint(s2), (unsigned)i2g);
  }

  int t = 1, phase = 0;
  while (t < M) {
    __syncthreads();
    // ---- pool: lanes 0-15 hold 8 waves x 2 ranks as UNIQUE u64 keys (v<<32 | ~i) ----
    uint4 sp = slots[phase * W + (lane & (W - 1))];
    u64 key;
    {
      unsigned vb = (lane & 8) ? sp.z : sp.x;
      unsigned ib = (lane & 8) ? sp.w : sp.y;
      key = ((u64)vb << 32) | (unsigned)(~ib);
    }
    if (lane >= 16) key = 0;
    u64 a1 = key, a2 = 0;
    pool16_top2(a1, a2);
    a1 = bcast64(a1); a2 = bcast64(a2);
    const int j1 = (int)(~(unsigned)a1);
    const int j2 = (int)(~(unsigned)a2);
    const float v2f = __uint_as_float((unsigned)(a2 >> 32));
    // second extraction (#3/#4): VALU-only, overlaps the pq LDS loads below
    u64 b1 = (key == a1 || key == a2) ? 0ull : key, b2 = 0;
    pool16_top2(b1, b2);
    b1 = bcast64(b1); b2 = bcast64(b2);

    const float4 c1 = pq[j1];
    const float4 c2 = pq[j2];

    const int room = M - t;
    float cx[4], cy[4], cz[4];
    cx[0] = c1.x; cy[0] = c1.y; cz[0] = c1.z;
    int p = 1;
    unsigned seen = 1u << ((j1 & (T - 1)) >> 6);
    bool capped = false;
    bool hit = (room >= 2) && (v2f > 0.f) &&
               (d2_rn(c2.x, c2.y, c2.z, c1.x, c1.y, c1.z) >= v2f);
    if (hit) {
      cx[1] = c2.x; cy[1] = c2.y; cz[1] = c2.z; p = 2;
      unsigned wb = 1u << ((j2 & (T - 1)) >> 6);
      if (seen & wb) capped = true;   // wave's stored top-2 exhausted -> stop after
      seen |= wb;
      if (!capped && room >= 3) {
        const float v3 = __uint_as_float((unsigned)(b1 >> 32));
        if (v3 > 0.f) {
          const int j3 = (int)(~(unsigned)b1);
          const float4 c3 = pq[j3];
          if (d2_rn(c3.x, c3.y, c3.z, c1.x, c1.y, c1.z) >= v3 &&
              d2_rn(c3.x, c3.y, c3.z, c2.x, c2.y, c2.z) >= v3) {
            cx[2] = c3.x; cy[2] = c3.y; cz[2] = c3.z; p = 3;
            unsigned wb3 = 1u << ((j3 & (T - 1)) >> 6);
            if (seen & wb3) capped = true;
            seen |= wb3;
            if (!capped && room >= 4) {
              const float v4 = __uint_as_float((unsigned)(b2 >> 32));
              if (v4 > 0.f) {
                const int j4 = (int)(~(unsigned)b2);
                const float4 c4 = pq[j4];
                if (d2_rn(c4.x, c4.y, c4.z, c1.x, c1.y, c1.z) >= v4 &&
                    d2_rn(c4.x, c4.y, c4.z, c2.x, c2.y, c2.z) >= v4 &&
                    d2_rn(c4.x, c4.y, c4.z, c3.x, c3.y, c3.z) >= v4) {
                  cx[3] = c4.x; cy[3] = c4.y; cz[3] = c4.z; p = 4;
                }
              }
            }
          }
        }
      }
    }

    if (tid == 0) {
      #pragma unroll
      for (int mm = 0; mm < 4; ++mm)
        if (mm < p) {
          O[3 * (t + mm)] = cx[mm]; O[3 * (t + mm) + 1] = cy[mm]; O[3 * (t + mm) + 2] = cz[mm];
        }
    }

    v1 = -1.f; v2 = -1.f; i1 = 0; i2 = 0;
    switch (p) {
      case 1:  FPS_UPD(1); break;
      case 2:  FPS_UPD(2); break;
      case 3:  FPS_UPD(3); break;
      default: FPS_UPD(4); break;
    }

    {
      float r1b = v1, r2b = v2;
      wave_top2_vals(r1b, r2b);
      float s1 = readlane_f(r1b, 63), s2 = readlane_f(r2b, 63);
      int i1g, i2g;
      wave_recover_idx(v1, i1, v2, i2, s1, s2, lane, i1g, i2g);
      if (lane == 0)
        slots[(phase ^ 1) * W + wv] = make_uint4(__float_as_uint(s1), (unsigned)i1g,
                                                 __float_as_uint(s2), (unsigned)i2g);
    }
    phase ^= 1;
    t += p;
  }
}

template<int N, int M, int NPT>
__global__ __launch_bounds__(512, 2) void fps_kernel(const float* __restrict__ pos,
                                                     float* __restrict__ out) {
  __shared__ __align__(16) char smem[16 * N + 2 * 8 * 16];
  fps_body<N, M, NPT, 512>(pos + (size_t)blockIdx.x * N * 3,
                           out + (size_t)blockIdx.x * M * 3, smem);
}

// ------------- per-source g[j] = x_j @ W1x + pos_j @ W1p  (tiny GEMM) -------------
template<int C, int H>
__global__ void g_kernel(const float* __restrict__ x, const float* __restrict__ pos,
                         const float* __restrict__ W, float* __restrict__ g, int rows) {
  int idx = blockIdx.x * 256 + threadIdx.x;
  if (idx >= rows * H) return;
  int row = idx / H, h = idx - row * H;
  const float* xr = x + (size_t)row * C;
  const float* pr = pos + (size_t)row * 3;
  float acc = 0.f;
  for (int c = 0; c < C; ++c) acc = fmaf(xr[c], W[c * H + h], acc);
  #pragma unroll
  for (int c = 0; c < 3; ++c) acc = fmaf(pr[c], W[(C + c) * H + h], acc);
  g[idx] = acc;
}

// ---------------- SA layer body (templated on thread count T) ----------------
template<int N, int H, int C, int T>
constexpr int sa_smem_bytes() {
  constexpr int TPS = C / 2, SG = T / TPS, JT = SG * 4, STRIDE = JT + 4;
  constexpr int SCR = (SG * C > 512) ? SG * C : 512;
  return H * C * 2 + N * 4 + H * 4 + STRIDE * H * 4 + SCR * 4 + 64 * 4 + 8 * 4 + 8 * 4;
}

template<int N, int H, int C, int QB, int T>
static __device__ void sa_body(const float* __restrict__ srcb,  // [N,3]
                               const float* __restrict__ gb,    // [N,H]
                               const float* __restrict__ qposb, // [M,3]
                               const float* __restrict__ W2, const float* __restrict__ b1v,
                               const float* __restrict__ W1p, const float* __restrict__ b2v,
                               float r2, int M, float* __restrict__ outb, int qtile,
                               char* smem) {
  constexpr int TPS = C / 2;
  constexpr int SG  = T / TPS;
  constexpr int JT  = SG * 4;
  constexpr int STRIDE = JT + 4;
  constexpr int SCR = (SG * C > 512) ? SG * C : 512;
  const int tid = threadIdx.x;
  const int sgi = tid / TPS;
  const int c2 = 2 * (tid - sgi * TPS);

  __hip_bfloat16* sW2h = (__hip_bfloat16*)smem;          // H*C*2
  float* sD2  = (float*)(smem + H * C * 2);              // N
  float* sT   = sD2 + N;                                 // H
  float* sHj  = sT + H;                                  // STRIDE*H (16B aligned)
  float* sScr = sHj + STRIDE * H;                        // SCR
  int*   sNbr = (int*)(sScr + SCR);                      // 64
  int*   sWS  = sNbr + 64;                               // 8
  int*   sIv  = sWS + 8;   // [0]=Cnt [1]=Nn [2]=Nc [3]=Bin [4]=Before [5]=TauI
  float* sFv  = (float*)(sIv + 6);  // [0]=TauV

  int*   sHist  = (int*)sScr;
  float* sCand  = sScr + 256;
  int*   sCandI = (int*)(sScr + 320);
  float* sRed   = sScr;

  for (int e = tid; e < H * C; e += T) sW2h[e] = __float2bfloat16(W2[e]);

  for (int qi = 0; qi < QB; ++qi) {
    const int i = qtile * QB + qi;
    const float* qp = qposb + (size_t)i * 3;
    const float qx = qp[0], qy = qp[1], qz = qp[2];
    const float qq = __fadd_rn(__fadd_rn(__fmul_rn(qx, qx), __fmul_rn(qy, qy)),
                               __fmul_rn(qz, qz));
    if (tid < H)
      sT[tid] = fmaf(qx, W1p[tid], fmaf(qy, W1p[H + tid], fmaf(qz, W1p[2 * H + tid], -b1v[tid])));
    if (tid == 0) { sIv[0] = 0; sIv[1] = 0; sIv[2] = 0; }
    if (tid < 256) sHist[tid] = 0;
    __syncthreads();

    // ---- pass 1: d2 (reference formula, exact rounding) + in-radius count ----
    int lc = 0;
    for (int j = tid; j < N; j += T) {
      float sx = srcb[3 * j], sy = srcb[3 * j + 1], sz = srcb[3 * j + 2];
      float ss  = __fadd_rn(__fadd_rn(__fmul_rn(sx, sx), __fmul_rn(sy, sy)), __fmul_rn(sz, sz));
      float dot = __fadd_rn(__fadd_rn(__fmul_rn(qx, sx), __fmul_rn(qy, sy)), __fmul_rn(qz, sz));
      float d2  = __fsub_rn(__fadd_rn(qq, ss), __fmul_rn(2.0f, dot));
      sD2[j] = d2;
      lc += (d2 <= r2) ? 1 : 0;
    }
    #pragma unroll
    for (int off = 32; off > 0; off >>= 1) lc += __shfl_xor(lc, off, 64);
    if ((tid & 63) == 0) atomicAdd(&sIv[0], lc);
    __syncthreads();
    const int cnt = sIv[0];

    // ---- exact rank-64 threshold (lexicographic (d2, idx), matches lax.top_k) ----
    float tauv; int taui;
    if (cnt <= 64) {
      tauv = r2; taui = 0x7fffffff;
    } else {
      const float scale = 256.0f / r2;
      for (int j = tid; j < N; j += T) {
        float d2 = sD2[j];
        if (d2 <= r2) {
          int bin = (int)(d2 * scale);
          bin = bin < 0 ? 0 : (bin > 255 ? 255 : bin);
          atomicAdd(&sHist[bin], 1);
        }
      }
      __syncthreads();
      int cbin = (tid < 256) ? sHist[tid] : 0;
      int lane = tid & 63, wvi = tid >> 6;
      int v = cbin;
      #pragma unroll
      for (int off = 1; off < 64; off <<= 1) {
        int o = __shfl_up(v, off, 64);
        if (lane >= off) v += o;
      }
      if (lane == 63) sWS[wvi] = v;
      __syncthreads();
      int wadd = 0;
      for (int w = 0; w < wvi; ++w) wadd += sWS[w];
      int incl = v + wadd, excl = incl - cbin;
      if (tid < 256 && excl < 64 && incl >= 64) { sIv[3] = tid; sIv[4] = excl; }
      __syncthreads();
      const int bstar = sIv[3];
      const int kneed = 64 - sIv[4];
      for (int j = tid; j < N; j += T) {
        float d2 = sD2[j];
        if (d2 <= r2) {
          int bin = (int)(d2 * scale);
          bin = bin < 0 ? 0 : (bin > 255 ? 255 : bin);
          if (bin == bstar) {
            int p = atomicAdd(&sIv[2], 1);
            if (p < 64) { sCand[p] = d2; sCandI[p] = j; }
          }
        }
      }
      __syncthreads();
      if (tid == 0) {
        int nc = sIv[2] < 64 ? sIv[2] : 64;
        for (int a = 1; a < nc; ++a) {
          float dv = sCand[a]; int di = sCandI[a];
          int p = a - 1;
          while (p >= 0 && (sCand[p] > dv || (sCand[p] == dv && sCandI[p] > di))) {
            sCand[p + 1] = sCand[p]; sCandI[p + 1] = sCandI[p]; --p;
          }
          sCand[p + 1] = dv; sCandI[p + 1] = di;
        }
        int kk = (kneed < nc ? kneed : nc) - 1; if (kk < 0) kk = 0;
        sFv[0] = sCand[kk]; sIv[5] = sCandI[kk];
      }
      __syncthreads();
      tauv = sFv[0]; taui = sIv[5];
    }

    // ---- compact neighbor list (set membership only; order irrelevant for max) ----
    for (int j = tid; j < N; j += T) {
      float d2 = sD2[j];
      if (d2 < tauv || (d2 == tauv && j <= taui)) {
        int p = atomicAdd(&sIv[1], 1);
        if (p < 64) sNbr[p] = j;
      }
    }
    __syncthreads();
    const int nn = sIv[1] < 64 ? sIv[1] : 64;

    // ---- MLP: h = ReLU(g[j]-t[i]);  out_c = max_j (h @ W2)_c + b2_c ----
    float m0 = -FLT_MAX, m1 = -FLT_MAX;
    for (int t0 = 0; t0 < nn; t0 += JT) {
      int jt = nn - t0; if (jt > JT) jt = JT;
      __syncthreads();
      for (int e = tid; e < JT * H; e += T) {
        int jj = e / H, h = e - jj * H;
        float hv = 0.f;
        if (jj < jt) {
          int j = sNbr[t0 + jj];
          hv = gb[(size_t)j * H + h] - sT[h];
          hv = hv > 0.f ? hv : 0.f;
        }
        sHj[h * STRIDE + jj] = hv;
      }
      __syncthreads();
      float a0 = 0, a1 = 0, a2 = 0, a3 = 0, c0 = 0, c1 = 0, c2a = 0, c3 = 0;
      const int jbase = sgi * 4;
      for (int h = 0; h < H; ++h) {
        float4 hv = *reinterpret_cast<const float4*>(&sHj[h * STRIDE + jbase]);
        __hip_bfloat162 wp = *reinterpret_cast<const __hip_bfloat162*>(&sW2h[h * C + c2]);
        float wx = __bfloat162float(wp.x), wy = __bfloat162float(wp.y);
        a0 = fmaf(hv.x, wx, a0); a1 = fmaf(hv.y, wx, a1);
        a2 = fmaf(hv.z, wx, a2); a3 = fmaf(hv.w, wx, a3);
        c0 = fmaf(hv.x, wy, c0); c1 = fmaf(hv.y, wy, c1);
        c2a = fmaf(hv.z, wy, c2a); c3 = fmaf(hv.w, wy, c3);
      }
      if (jbase + 0 < jt) { m0 = fmaxf(m0, a0); m1 = fmaxf(m1, c0); }
      if (jbase + 1 < jt) { m0 = fmaxf(m0, a1); m1 = fmaxf(m1, c1); }
      if (jbase + 2 < jt) { m0 = fmaxf(m0, a2); m1 = fmaxf(m1, c2a); }
      if (jbase + 3 < jt) { m0 = fmaxf(m0, a3); m1 = fmaxf(m1, c3); }
    }
    __syncthreads();
    sRed[sgi * C + c2]     = m0;
    sRed[sgi * C + c2 + 1] = m1;
    __syncthreads();
    if (tid < TPS) {
      int c = 2 * tid;
      float M0 = sRed[c], M1 = sRed[c + 1];
      #pragma unroll
      for (int s2 = 1; s2 < SG; ++s2) {
        M0 = fmaxf(M0, sRed[s2 * C + c]);
        M1 = fmaxf(M1, sRed[s2 * C + c + 1]);
      }
      float o0 = nn > 0 ? M0 + b2v[c]     : 0.f;
      float o1 = nn > 0 ? M1 + b2v[c + 1] : 0.f;
      float* orow = outb + (size_t)i * C;
      orow[c] = o0; orow[c + 1] = o1;
    }
    __syncthreads();
  }
}

template<int N, int H, int C, int QB>
__global__ __launch_bounds__(256) void sa_kernel(
    const float* __restrict__ src, const float* __restrict__ g,
    const float* __restrict__ qpos, const float* __restrict__ W2,
    const float* __restrict__ b1v, const float* __restrict__ W1p,
    const float* __restrict__ b2v, float r2, int M, float* __restrict__ out) {
  __shared__ __align__(16) char smem[sa_smem_bytes<N, H, C, 256>()];
  const int b = blockIdx.y;
  sa_body<N, H, C, QB, 256>(src + (size_t)b * N * 3, g + (size_t)b * N * H,
                            qpos + (size_t)b * M * 3, W2, b1v, W1p, b2v, r2, M,
                            out + (size_t)b * M * C, blockIdx.x, smem);
}

// ------- fused: blocks 0-7 run FPS (next layer's sampling), rest run SA (this layer) -------
template<int NF, int MF, int NPTF, int NS, int HS, int CS, int QB, int SAB>
__global__ __launch_bounds__(512, 2) void fused_kernel(
    const float* __restrict__ fsrc, float* __restrict__ fdst,
    const float* __restrict__ src, const float* __restrict__ g,
    const float* __restrict__ qpos, const float* __restrict__ W2,
    const float* __restrict__ b1v, const float* __restrict__ W1p,
    const float* __restrict__ b2v, float r2, int M, float* __restrict__ out) {
  constexpr int FPS_BYTES = 16 * NF + 2 * 8 * 16;
  constexpr int SA_BYTES  = sa_smem_bytes<NS, HS, CS, 512>();
  constexpr int SMEM = FPS_BYTES > SA_BYTES ? FPS_BYTES : SA_BYTES;
  __shared__ __align__(16) char smem[SMEM];
  if (blockIdx.x < 8) {
    __builtin_amdgcn_s_setprio(3);  // FPS is the latency-critical serial chain
    fps_body<NF, MF, NPTF, 512>(fsrc + (size_t)blockIdx.x * NF * 3,
                                fdst + (size_t)blockIdx.x * MF * 3, smem);
    return;
  }
  const int bi = blockIdx.x - 8;
  const int qt = bi % SAB;
  const int b  = bi / SAB;
  sa_body<NS, HS, CS, QB, 512>(src + (size_t)b * NS * 3, g + (size_t)b * NS * HS,
                               qpos + (size_t)b * M * 3, W2, b1v, W1p, b2v, r2, M,
                               out + (size_t)b * M * CS, qt, smem);
}

// ---------------- tail: copy p3 and synthesize batch ids into d_out ----------------
__global__ void tail_kernel(const float* __restrict__ p3, float* __restrict__ d_out) {
  int i = blockIdx.x * 256 + threadIdx.x;
  if (i < 8 * 512 * 3) d_out[524288 + i] = p3[i];
  if (i < 8 * 512)     d_out[536576 + i] = (float)(i >> 9);
}

extern "C" void kernel_launch(void* const* d_in, const int* in_sizes, int n_in,
                              void* d_out, int out_size, void* d_ws, size_t ws_size,
                              hipStream_t stream) {
  (void)in_sizes; (void)n_in; (void)out_size; (void)ws_size;
  const float* pos = (const float*)d_in[0];
  const float* w11 = (const float*)d_in[2];
  const float* b11 = (const float*)d_in[3];
  const float* w12 = (const float*)d_in[4];
  const float* b12 = (const float*)d_in[5];
  const float* w21 = (const float*)d_in[6];
  const float* b21 = (const float*)d_in[7];
  const float* w22 = (const float*)d_in[8];
  const float* b22 = (const float*)d_in[9];
  const float* w31 = (const float*)d_in[10];
  const float* b31 = (const float*)d_in[11];
  const float* w32 = (const float*)d_in[12];
  const float* b32 = (const float*)d_in[13];

  float* ws = (float*)d_ws;
  float* p1 = ws; ws += 8 * 2048 * 3;
  float* p2 = ws; ws += 8 * 512 * 3;
  float* p3 = ws; ws += 8 * 512 * 3;
  float* g1 = ws; ws += 8 * 4096 * 32;
  float* x1 = ws; ws += 8 * 2048 * 32;
  float* g2 = ws; ws += 8 * 2048 * 64;
  float* x2 = ws; ws += 8 * 512 * 64;
  float* g3 = ws; ws += 8 * 512 * 128;
  float* x3 = (float*)d_out;

  // layer 1: g1 (tiny, independent), then FPS1 (the long serial chain)
  g_kernel<3, 32><<<dim3(8 * 4096 * 32 / 256), dim3(256), 0, stream>>>(pos, pos, w11, g1, 8 * 4096);
  fps_kernel<4096, 2048, 8><<<dim3(8), dim3(512), 0, stream>>>(pos, p1);

  // fused A: fps2 (p1->p2) overlapped with sa1 (pos,g1,p1 -> x1); SAB = 2048/8 = 256
  fused_kernel<2048, 512, 4, 4096, 32, 32, 8, 256><<<dim3(8 + 8 * 256), dim3(512), 0, stream>>>(
      p1, p2, pos, g1, p1, w12, b11, w11 + 3 * 32, b12, 0.04f, 2048, x1);

  g_kernel<32, 64><<<dim3(8 * 2048 * 64 / 256), dim3(256), 0, stream>>>(x1, p1, w21, g2, 8 * 2048);

  // fused B: fps3 (p2->p3) overlapped with sa2 (p1,g2,p2 -> x2); SAB = 512/8 = 64
  fused_kernel<512, 512, 1, 2048, 64, 64, 8, 64><<<dim3(8 + 8 * 64), dim3(512), 0, stream>>>(
      p2, p3, p1, g2, p2, w22, b21, w21 + 32 * 64, b22, 0.16f, 512, x2);

  g_kernel<64, 128><<<dim3(8 * 512 * 128 / 256), dim3(256), 0, stream>>>(x2, p2, w31, g3, 8 * 512);

  sa_kernel<512, 128, 128, 8><<<dim3(64, 8), dim3(256), 0, stream>>>(
      p2, g3, p3, w32, b31, w31 + 64 * 128, b32, 1.0f, 512, x3);

  tail_kernel<<<dim3(48), dim3(256), 0, stream>>>(p3, (float*)d_out);
}

// Round 14
// 2126.336 us; speedup vs baseline: 1.0290x; 1.0290x over previous
//
#include <hip/hip_runtime.h>
#include <hip/hip_bf16.h>
#include <float.h>

typedef unsigned long long u64;

// ---------- exact-rounding helpers (match numpy fp32, no FMA contraction) ----------
static __device__ __forceinline__ float d2_rn(float ax, float ay, float az,
                                              float bx, float by, float bz) {
  float dx = __fsub_rn(ax, bx), dy = __fsub_rn(ay, by), dz = __fsub_rn(az, bz);
  return __fadd_rn(__fadd_rn(__fmul_rn(dx, dx), __fmul_rn(dy, dy)), __fmul_rn(dz, dz));
}

// ---------------- DPP primitives ----------------
template<int CTRL>
static __device__ __forceinline__ float dpp_f32(float x) {
  return __int_as_float(__builtin_amdgcn_update_dpp(0, __float_as_int(x), CTRL, 0xF, 0xF, true));
}

template<int CTRL>
static __device__ __forceinline__ int dpp_min_i32(int x) {
  int b = __builtin_amdgcn_update_dpp(0x7fffffff, x, CTRL, 0xF, 0xF, false);
  return x < b ? x : b;
}

// u64 cross-lane move (two 32-bit halves); bound_ctrl=1 -> invalid lanes read 0 (= -inf key)
template<int CTRL>
static __device__ __forceinline__ u64 dpp_u64(u64 x) {
  unsigned lo = (unsigned)__builtin_amdgcn_update_dpp(0, (int)(unsigned)x, CTRL, 0xF, 0xF, true);
  unsigned hi = (unsigned)__builtin_amdgcn_update_dpp(0, (int)(unsigned)(x >> 32), CTRL, 0xF, 0xF, true);
  return ((u64)hi << 32) | lo;
}

// merge two descending top-2 u64 lists (proven rounds 2-12)
static __device__ __forceinline__ void merge2(u64& a1, u64& a2, u64 b1, u64 b2) {
  bool agt = a1 > b1;
  u64 m1 = agt ? a1 : b1;
  u64 lo = agt ? b1 : a1;
  u64 cs = agt ? a2 : b2;
  a1 = m1;
  a2 = lo > cs ? lo : cs;
}

template<int CTRL>
static __device__ __forceinline__ void merge_dpp(u64& a1, u64& a2) {
  u64 b1 = dpp_u64<CTRL>(a1);
  u64 b2 = dpp_u64<CTRL>(a2);
  merge2(a1, a2, b1, b2);
}

// 16-lane u64 top-2 (patterns stay within the 16-lane row; lanes 0-15 all uniform after)
static __device__ __forceinline__ void pool16_top2(u64& a1, u64& a2) {
  merge_dpp<0xB1>(a1, a2);   // xor 1
  merge_dpp<0x4E>(a1, a2);   // xor 2
  merge_dpp<0x141>(a1, a2);  // row_half_mirror
  merge_dpp<0x140>(a1, a2);  // row_mirror: 16-uniform
}

static __device__ __forceinline__ u64 bcast64(u64 x) {
  unsigned lo = (unsigned)__builtin_amdgcn_readfirstlane((int)(unsigned)x);
  unsigned hi = (unsigned)__builtin_amdgcn_readfirstlane((int)(x >> 32));
  return ((u64)hi << 32) | lo;
}

// ---- value-only wave top-2 + index recovery ----
template<int CTRL>
static __device__ __forceinline__ void top2_step(float& v1, float& v2) {
  float b1 = dpp_f32<CTRL>(v1);
  float b2 = dpp_f32<CTRL>(v2);
  float m1 = fmaxf(v1, b1);
  float lo = fminf(v1, b1);
  v2 = fmaxf(lo, fmaxf(v2, b2));
  v1 = m1;
}

static __device__ __forceinline__ void wave_top2_vals(float& v1, float& v2) {
  top2_step<0xB1>(v1, v2);
  top2_step<0x4E>(v1, v2);
  top2_step<0x141>(v1, v2);
  top2_step<0x140>(v1, v2);
  top2_step<0x142>(v1, v2);
  top2_step<0x143>(v1, v2);  // lane 63 = full wave
}

static __device__ __forceinline__ int wave_min_idx(int c) {
  c = dpp_min_i32<0xB1>(c);  c = dpp_min_i32<0x4E>(c);
  c = dpp_min_i32<0x141>(c); c = dpp_min_i32<0x140>(c);
  c = dpp_min_i32<0x142>(c); c = dpp_min_i32<0x143>(c);
  return __builtin_amdgcn_readlane(c, 63);
}

static __device__ __forceinline__ float readlane_f(float x, int l) {
  return __int_as_float(__builtin_amdgcn_readlane(__float_as_int(x), l));
}

static __device__ __forceinline__ void wave_recover_idx(float lv1, int li1, float lv2, int li2,
                                                        float s1, float s2, int lane,
                                                        int& i1g, int& i2g) {
  u64 b1 = __ballot(lv1 == s1);
  int lw;
  if (__popcll(b1) == 1) {
    lw = __ffsll(b1) - 1;
    i1g = __builtin_amdgcn_readlane(li1, lw);
  } else {
    i1g = wave_min_idx(lv1 == s1 ? li1 : 0x7fffffff);
    lw = __ffsll(__ballot(lv1 == s1 && li1 == i1g)) - 1;
  }
  float wlv = (lane == lw) ? lv2 : lv1;
  int   wli = (lane == lw) ? li2 : li1;
  u64 b2 = __ballot(wlv == s2);
  if (__popcll(b2) == 1) {
    i2g = __builtin_amdgcn_readlane(wli, __ffsll(b2) - 1);
  } else {
    i2g = wave_min_idx(wlv == s2 ? wli : 0x7fffffff);
  }
}

#define FPS_UPD(PP)                                                                    \
  { _Pragma("unroll")                                                                  \
    for (int k = 0; k < NPT; ++k) {                                                    \
      float m = md[k];                                                                 \
      _Pragma("unroll")                                                                \
      for (int mm = 0; mm < (PP); ++mm)                                                \
        m = fminf(m, d2_rn(px[k], py[k], pz[k], cx[mm], cy[mm], cz[mm]));              \
      md[k] = m; int j = tid + k * T;                                                  \
      if (m > v2) { if (m > v1) { v2=v1; i2=i1; v1=m; i1=j; } else { v2=m; i2=j; } }   \
    } }

// ------- FPS: u64-key pool, accept up to MAXP/round; wave-gated repair for mild rejects -------
// Repair soundness: a rejected candidate k with post-update value m~ is still the exact next
// selection iff key(m~,idx) > (next sorted pool key) AND k's wave has not yet contributed an
// accepted point this round (otherwise that wave's #3 is unbounded by the pool). MAXP=2 for
// fused (short chain under CU contention), MAXP=4 for dedicated CUs.
template<int N, int M, int NPT, int T, int MAXP>
static __device__ void fps_body(const float* __restrict__ P, float* __restrict__ O,
                                char* smem) {
  constexpr int W = T / 64;
  static_assert(N == T * NPT, "layout");
  float4* pq = (float4*)smem;            // [N] interleaved coords (x,y,z,0)
  uint4* slots = (uint4*)(pq + N);       // [2][W]: (v1,i1,v2,i2)
  const int tid = threadIdx.x;
  const int lane = tid & 63, wv = tid >> 6;

  for (int j = tid; j < N; j += T)
    pq[j] = make_float4(P[3 * j], P[3 * j + 1], P[3 * j + 2], 0.f);
  __syncthreads();

  const float4 c0 = pq[0];
  if (tid == 0) { O[0] = c0.x; O[1] = c0.y; O[2] = c0.z; }

  float md[NPT], px[NPT], py[NPT], pz[NPT];
  float v1 = -1.f, v2 = -1.f; int i1 = 0, i2 = 0;
  #pragma unroll
  for (int k = 0; k < NPT; ++k) {
    int j = tid + k * T;  // ascending j -> strict '>' keeps first index on ties
    float4 p = pq[j];
    px[k] = p.x; py[k] = p.y; pz[k] = p.z;
    float m = d2_rn(p.x, p.y, p.z, c0.x, c0.y, c0.z);
    md[k] = m;
    if (m > v2) { if (m > v1) { v2=v1; i2=i1; v1=m; i1=j; } else { v2=m; i2=j; } }
  }

  {
    float r1 = v1, r2 = v2;
    wave_top2_vals(r1, r2);
    float s1 = readlane_f(r1, 63), s2 = readlane_f(r2, 63);
    int i1g, i2g;
    wave_recover_idx(v1, i1, v2, i2, s1, s2, lane, i1g, i2g);
    if (lane == 0)
      slots[wv] = make_uint4(__float_as_uint(s1), (unsigned)i1g,
                             __float_as_uint(s2), (unsigned)i2g);
  }

  int t = 1, phase = 0;
  while (t < M) {
    __syncthreads();
    // ---- pool: lanes 0-15 hold 8 waves x 2 ranks as UNIQUE u64 keys (v<<32 | ~i) ----
    uint4 sp = slots[phase * W + (lane & (W - 1))];
    u64 key;
    {
      unsigned vb = (lane & 8) ? sp.z : sp.x;
      unsigned ib = (lane & 8) ? sp.w : sp.y;
      key = ((u64)vb << 32) | (unsigned)(~ib);
    }
    if (lane >= 16) key = 0;
    u64 a1 = key, a2 = 0;
    pool16_top2(a1, a2);
    a1 = bcast64(a1); a2 = bcast64(a2);
    const int j1 = (int)(~(unsigned)a1);
    const int j2 = (int)(~(unsigned)a2);
    const float v2f = __uint_as_float((unsigned)(a2 >> 32));
    u64 b1 = 0, b2 = 0;
    if constexpr (MAXP >= 3) {
      // second extraction (#3/#4): VALU-only, overlaps the pq LDS loads below
      b1 = (key == a1 || key == a2) ? 0ull : key;
      pool16_top2(b1, b2);
      b1 = bcast64(b1); b2 = bcast64(b2);
    }

    const float4 c1 = pq[j1];
    const float4 c2 = pq[j2];

    const int room = M - t;
    float cx[4], cy[4], cz[4];
    cx[0] = c1.x; cy[0] = c1.y; cz[0] = c1.z;
    int p = 1;
    unsigned seen = 1u << ((j1 & (T - 1)) >> 6);
    bool stop = false;

    // ---- candidate 2 ----
    if (room >= 2 && v2f > 0.f) {
      float dd = d2_rn(c2.x, c2.y, c2.z, c1.x, c1.y, c1.z);
      bool acc = (dd >= v2f);
      unsigned wb = 1u << ((j2 & (T - 1)) >> 6);
      if constexpr (MAXP >= 3) {
        if (!acc && !(seen & wb)) {
          // repair (wave-gated): post-update value of c2 is exactly dd; every other
          // competitor is bounded by a live pool key <= b1 -> exact if key(dd,j2) > b1
          u64 kr = ((u64)__float_as_uint(dd) << 32) | (unsigned)(~j2);
          acc = (kr > b1);
        }
      }
      if (acc) {
        cx[1] = c2.x; cy[1] = c2.y; cz[1] = c2.z; p = 2;
        if (seen & wb) stop = true;   // wave's stored top-2 exhausted
        seen |= wb;
      } else stop = true;
    } else stop = true;

    if constexpr (MAXP >= 3) {
      // ---- candidate 3 ----
      if (!stop && room >= 3) {
        const float v3 = __uint_as_float((unsigned)(b1 >> 32));
        if (v3 > 0.f) {
          const int j3 = (int)(~(unsigned)b1);
          const float4 c3 = pq[j3];
          float mn = fminf(d2_rn(c3.x, c3.y, c3.z, c1.x, c1.y, c1.z),
                           d2_rn(c3.x, c3.y, c3.z, cx[1], cy[1], cz[1]));
          bool acc = (mn >= v3);
          unsigned wb3 = 1u << ((j3 & (T - 1)) >> 6);
          if (!acc && !(seen & wb3)) {
            float m3 = fminf(v3, mn);
            u64 kr = ((u64)__float_as_uint(m3) << 32) | (unsigned)(~j3);
            acc = (kr > b2);          // remaining live bound = b2 (wave-gated)
          }
          if (acc) {
            cx[2] = c3.x; cy[2] = c3.y; cz[2] = c3.z; p = 3;
            if (seen & wb3) stop = true;
            seen |= wb3;
          } else stop = true;
        } else stop = true;
      }
      // ---- candidate 4 (no repair: no next-key bound available) ----
      if (!stop && room >= 4) {
        const float v4 = __uint_as_float((unsigned)(b2 >> 32));
        if (v4 > 0.f) {
          const int j4 = (int)(~(unsigned)b2);
          const float4 c4 = pq[j4];
          float mn = fminf(fminf(d2_rn(c4.x, c4.y, c4.z, c1.x, c1.y, c1.z),
                                 d2_rn(c4.x, c4.y, c4.z, cx[1], cy[1], cz[1])),
                           d2_rn(c4.x, c4.y, c4.z, cx[2], cy[2], cz[2]));
          if (mn >= v4) { cx[3] = c4.x; cy[3] = c4.y; cz[3] = c4.z; p = 4; }
        }
      }
    }

    if (tid == 0) {
      #pragma unroll
      for (int mm = 0; mm < 4; ++mm)
        if (mm < p) {
          O[3 * (t + mm)] = cx[mm]; O[3 * (t + mm) + 1] = cy[mm]; O[3 * (t + mm) + 2] = cz[mm];
        }
    }

    v1 = -1.f; v2 = -1.f; i1 = 0; i2 = 0;
    switch (p) {
      case 1:  FPS_UPD(1); break;
      case 2:  FPS_UPD(2); break;
      case 3:  FPS_UPD(3); break;
      default: FPS_UPD(4); break;
    }

    {
      float r1b = v1, r2b = v2;
      wave_top2_vals(r1b, r2b);
      float s1 = readlane_f(r1b, 63), s2 = readlane_f(r2b, 63);
      int i1g, i2g;
      wave_recover_idx(v1, i1, v2, i2, s1, s2, lane, i1g, i2g);
      if (lane == 0)
        slots[(phase ^ 1) * W + wv] = make_uint4(__float_as_uint(s1), (unsigned)i1g,
                                                 __float_as_uint(s2), (unsigned)i2g);
    }
    phase ^= 1;
    t += p;
  }
}

template<int N, int M, int NPT>
__global__ __launch_bounds__(512, 2) void fps_kernel(const float* __restrict__ pos,
                                                     float* __restrict__ out) {
  __shared__ __align__(16) char smem[16 * N + 2 * 8 * 16];
  fps_body<N, M, NPT, 512, 4>(pos + (size_t)blockIdx.x * N * 3,
                              out + (size_t)blockIdx.x * M * 3, smem);
}

// ------------- per-source g[j] = x_j @ W1x + pos_j @ W1p  (tiny GEMM) -------------
template<int C, int H>
__global__ void g_kernel(const float* __restrict__ x, const float* __restrict__ pos,
                         const float* __restrict__ W, float* __restrict__ g, int rows) {
  int idx = blockIdx.x * 256 + threadIdx.x;
  if (idx >= rows * H) return;
  int row = idx / H, h = idx - row * H;
  const float* xr = x + (size_t)row * C;
  const float* pr = pos + (size_t)row * 3;
  float acc = 0.f;
  for (int c = 0; c < C; ++c) acc = fmaf(xr[c], W[c * H + h], acc);
  #pragma unroll
  for (int c = 0; c < 3; ++c) acc = fmaf(pr[c], W[(C + c) * H + h], acc);
  g[idx] = acc;
}

// ---------------- SA layer body (templated on thread count T) ----------------
template<int N, int H, int C, int T>
constexpr int sa_smem_bytes() {
  constexpr int TPS = C / 2, SG = T / TPS, JT = SG * 4, STRIDE = JT + 4;
  constexpr int SCR = (SG * C > 512) ? SG * C : 512;
  return H * C * 2 + N * 4 + H * 4 + STRIDE * H * 4 + SCR * 4 + 64 * 4 + 8 * 4 + 8 * 4;
}

template<int N, int H, int C, int QB, int T>
static __device__ void sa_body(const float* __restrict__ srcb,  // [N,3]
                               const float* __restrict__ gb,    // [N,H]
                               const float* __restrict__ qposb, // [M,3]
                               const float* __restrict__ W2, const float* __restrict__ b1v,
                               const float* __restrict__ W1p, const float* __restrict__ b2v,
                               float r2, int M, float* __restrict__ outb, int qtile,
                               char* smem) {
  constexpr int TPS = C / 2;
  constexpr int SG  = T / TPS;
  constexpr int JT  = SG * 4;
  constexpr int STRIDE = JT + 4;
  constexpr int SCR = (SG * C > 512) ? SG * C : 512;
  const int tid = threadIdx.x;
  const int sgi = tid / TPS;
  const int c2 = 2 * (tid - sgi * TPS);

  __hip_bfloat16* sW2h = (__hip_bfloat16*)smem;          // H*C*2
  float* sD2  = (float*)(smem + H * C * 2);              // N
  float* sT   = sD2 + N;                                 // H
  float* sHj  = sT + H;                                  // STRIDE*H (16B aligned)
  float* sScr = sHj + STRIDE * H;                        // SCR
  int*   sNbr = (int*)(sScr + SCR);                      // 64
  int*   sWS  = sNbr + 64;                               // 8
  int*   sIv  = sWS + 8;   // [0]=Cnt [1]=Nn [2]=Nc [3]=Bin [4]=Before [5]=TauI
  float* sFv  = (float*)(sIv + 6);  // [0]=TauV

  int*   sHist  = (int*)sScr;
  float* sCand  = sScr + 256;
  int*   sCandI = (int*)(sScr + 320);
  float* sRed   = sScr;

  for (int e = tid; e < H * C; e += T) sW2h[e] = __float2bfloat16(W2[e]);

  for (int qi = 0; qi < QB; ++qi) {
    const int i = qtile * QB + qi;
    const float* qp = qposb + (size_t)i * 3;
    const float qx = qp[0], qy = qp[1], qz = qp[2];
    const float qq = __fadd_rn(__fadd_rn(__fmul_rn(qx, qx), __fmul_rn(qy, qy)),
                               __fmul_rn(qz, qz));
    if (tid < H)
      sT[tid] = fmaf(qx, W1p[tid], fmaf(qy, W1p[H + tid], fmaf(qz, W1p[2 * H + tid], -b1v[tid])));
    if (tid == 0) { sIv[0] = 0; sIv[1] = 0; sIv[2] = 0; }
    if (tid < 256) sHist[tid] = 0;
    __syncthreads();

    // ---- pass 1: d2 (reference formula, exact rounding) + in-radius count ----
    int lc = 0;
    for (int j = tid; j < N; j += T) {
      float sx = srcb[3 * j], sy = srcb[3 * j + 1], sz = srcb[3 * j + 2];
      float ss  = __fadd_rn(__fadd_rn(__fmul_rn(sx, sx), __fmul_rn(sy, sy)), __fmul_rn(sz, sz));
      float dot = __fadd_rn(__fadd_rn(__fmul_rn(qx, sx), __fmul_rn(qy, sy)), __fmul_rn(qz, sz));
      float d2  = __fsub_rn(__fadd_rn(qq, ss), __fmul_rn(2.0f, dot));
      sD2[j] = d2;
      lc += (d2 <= r2) ? 1 : 0;
    }
    #pragma unroll
    for (int off = 32; off > 0; off >>= 1) lc += __shfl_xor(lc, off, 64);
    if ((tid & 63) == 0) atomicAdd(&sIv[0], lc);
    __syncthreads();
    const int cnt = sIv[0];

    // ---- exact rank-64 threshold (lexicographic (d2, idx), matches lax.top_k) ----
    float tauv; int taui;
    if (cnt <= 64) {
      tauv = r2; taui = 0x7fffffff;
    } else {
      const float scale = 256.0f / r2;
      for (int j = tid; j < N; j += T) {
        float d2 = sD2[j];
        if (d2 <= r2) {
          int bin = (int)(d2 * scale);
          bin = bin < 0 ? 0 : (bin > 255 ? 255 : bin);
          atomicAdd(&sHist[bin], 1);
        }
      }
      __syncthreads();
      int cbin = (tid < 256) ? sHist[tid] : 0;
      int lane = tid & 63, wvi = tid >> 6;
      int v = cbin;
      #pragma unroll
      for (int off = 1; off < 64; off <<= 1) {
        int o = __shfl_up(v, off, 64);
        if (lane >= off) v += o;
      }
      if (lane == 63) sWS[wvi] = v;
      __syncthreads();
      int wadd = 0;
      for (int w = 0; w < wvi; ++w) wadd += sWS[w];
      int incl = v + wadd, excl = incl - cbin;
      if (tid < 256 && excl < 64 && incl >= 64) { sIv[3] = tid; sIv[4] = excl; }
      __syncthreads();
      const int bstar = sIv[3];
      const int kneed = 64 - sIv[4];
      for (int j = tid; j < N; j += T) {
        float d2 = sD2[j];
        if (d2 <= r2) {
          int bin = (int)(d2 * scale);
          bin = bin < 0 ? 0 : (bin > 255 ? 255 : bin);
          if (bin == bstar) {
            int p = atomicAdd(&sIv[2], 1);
            if (p < 64) { sCand[p] = d2; sCandI[p] = j; }
          }
        }
      }
      __syncthreads();
      if (tid == 0) {
        int nc = sIv[2] < 64 ? sIv[2] : 64;
        for (int a = 1; a < nc; ++a) {
          float dv = sCand[a]; int di = sCandI[a];
          int p = a - 1;
          while (p >= 0 && (sCand[p] > dv || (sCand[p] == dv && sCandI[p] > di))) {
            sCand[p + 1] = sCand[p]; sCandI[p + 1] = sCandI[p]; --p;
          }
          sCand[p + 1] = dv; sCandI[p + 1] = di;
        }
        int kk = (kneed < nc ? kneed : nc) - 1; if (kk < 0) kk = 0;
        sFv[0] = sCand[kk]; sIv[5] = sCandI[kk];
      }
      __syncthreads();
      tauv = sFv[0]; taui = sIv[5];
    }

    // ---- compact neighbor list (set membership only; order irrelevant for max) ----
    for (int j = tid; j < N; j += T) {
      float d2 = sD2[j];
      if (d2 < tauv || (d2 == tauv && j <= taui)) {
        int p = atomicAdd(&sIv[1], 1);
        if (p < 64) sNbr[p] = j;
      }
    }
    __syncthreads();
    const int nn = sIv[1] < 64 ? sIv[1] : 64;

    // ---- MLP: h = ReLU(g[j]-t[i]);  out_c = max_j (h @ W2)_c + b2_c ----
    float m0 = -FLT_MAX, m1 = -FLT_MAX;
    for (int t0 = 0; t0 < nn; t0 += JT) {
      int jt = nn - t0; if (jt > JT) jt = JT;
      __syncthreads();
      for (int e = tid; e < JT * H; e += T) {
        int jj = e / H, h = e - jj * H;
        float hv = 0.f;
        if (jj < jt) {
          int j = sNbr[t0 + jj];
          hv = gb[(size_t)j * H + h] - sT[h];
          hv = hv > 0.f ? hv : 0.f;
        }
        sHj[h * STRIDE + jj] = hv;
      }
      __syncthreads();
      float a0 = 0, a1 = 0, a2 = 0, a3 = 0, c0 = 0, c1 = 0, c2a = 0, c3 = 0;
      const int jbase = sgi * 4;
      for (int h = 0; h < H; ++h) {
        float4 hv = *reinterpret_cast<const float4*>(&sHj[h * STRIDE + jbase]);
        __hip_bfloat162 wp = *reinterpret_cast<const __hip_bfloat162*>(&sW2h[h * C + c2]);
        float wx = __bfloat162float(wp.x), wy = __bfloat162float(wp.y);
        a0 = fmaf(hv.x, wx, a0); a1 = fmaf(hv.y, wx, a1);
        a2 = fmaf(hv.z, wx, a2); a3 = fmaf(hv.w, wx, a3);
        c0 = fmaf(hv.x, wy, c0); c1 = fmaf(hv.y, wy, c1);
        c2a = fmaf(hv.z, wy, c2a); c3 = fmaf(hv.w, wy, c3);
      }
      if (jbase + 0 < jt) { m0 = fmaxf(m0, a0); m1 = fmaxf(m1, c0); }
      if (jbase + 1 < jt) { m0 = fmaxf(m0, a1); m1 = fmaxf(m1, c1); }
      if (jbase + 2 < jt) { m0 = fmaxf(m0, a2); m1 = fmaxf(m1, c2a); }
      if (jbase + 3 < jt) { m0 = fmaxf(m0, a3); m1 = fmaxf(m1, c3); }
    }
    __syncthreads();
    sRed[sgi * C + c2]     = m0;
    sRed[sgi * C + c2 + 1] = m1;
    __syncthreads();
    if (tid < TPS) {
      int c = 2 * tid;
      float M0 = sRed[c], M1 = sRed[c + 1];
      #pragma unroll
      for (int s2 = 1; s2 < SG; ++s2) {
        M0 = fmaxf(M0, sRed[s2 * C + c]);
        M1 = fmaxf(M1, sRed[s2 * C + c + 1]);
      }
      float o0 = nn > 0 ? M0 + b2v[c]     : 0.f;
      float o1 = nn > 0 ? M1 + b2v[c + 1] : 0.f;
      float* orow = outb + (size_t)i * C;
      orow[c] = o0; orow[c + 1] = o1;
    }
    __syncthreads();
  }
}

template<int N, int H, int C, int QB>
__global__ __launch_bounds__(256) void sa_kernel(
    const float* __restrict__ src, const float* __restrict__ g,
    const float* __restrict__ qpos, const float* __restrict__ W2,
    const float* __restrict__ b1v, const float* __restrict__ W1p,
    const float* __restrict__ b2v, float r2, int M, float* __restrict__ out) {
  __shared__ __align__(16) char smem[sa_smem_bytes<N, H, C, 256>()];
  const int b = blockIdx.y;
  sa_body<N, H, C, QB, 256>(src + (size_t)b * N * 3, g + (size_t)b * N * H,
                            qpos + (size_t)b * M * 3, W2, b1v, W1p, b2v, r2, M,
                            out + (size_t)b * M * C, blockIdx.x, smem);
}

// ------- fused: blocks 0-7 run FPS (next layer's sampling), rest run SA (this layer) -------
template<int NF, int MF, int NPTF, int NS, int HS, int CS, int QB, int SAB>
__global__ __launch_bounds__(512, 2) void fused_kernel(
    const float* __restrict__ fsrc, float* __restrict__ fdst,
    const float* __restrict__ src, const float* __restrict__ g,
    const float* __restrict__ qpos, const float* __restrict__ W2,
    const float* __restrict__ b1v, const float* __restrict__ W1p,
    const float* __restrict__ b2v, float r2, int M, float* __restrict__ out) {
  constexpr int FPS_BYTES = 16 * NF + 2 * 8 * 16;
  constexpr int SA_BYTES  = sa_smem_bytes<NS, HS, CS, 512>();
  constexpr int SMEM = FPS_BYTES > SA_BYTES ? FPS_BYTES : SA_BYTES;
  __shared__ __align__(16) char smem[SMEM];
  if (blockIdx.x < 8) {
    __builtin_amdgcn_s_setprio(3);  // FPS is the latency-critical serial chain
    // MAXP=2: short dependent chain — deep speculation regresses under SA contention
    fps_body<NF, MF, NPTF, 512, 2>(fsrc + (size_t)blockIdx.x * NF * 3,
                                   fdst + (size_t)blockIdx.x * MF * 3, smem);
    return;
  }
  const int bi = blockIdx.x - 8;
  const int qt = bi % SAB;
  const int b  = bi / SAB;
  sa_body<NS, HS, CS, QB, 512>(src + (size_t)b * NS * 3, g + (size_t)b * NS * HS,
                               qpos + (size_t)b * M * 3, W2, b1v, W1p, b2v, r2, M,
                               out + (size_t)b * M * CS, qt, smem);
}

// ---------------- tail: copy p3 and synthesize batch ids into d_out ----------------
__global__ void tail_kernel(const float* __restrict__ p3, float* __restrict__ d_out) {
  int i = blockIdx.x * 256 + threadIdx.x;
  if (i < 8 * 512 * 3) d_out[524288 + i] = p3[i];
  if (i < 8 * 512)     d_out[536576 + i] = (float)(i >> 9);
}

extern "C" void kernel_launch(void* const* d_in, const int* in_sizes, int n_in,
                              void* d_out, int out_size, void* d_ws, size_t ws_size,
                              hipStream_t stream) {
  (void)in_sizes; (void)n_in; (void)out_size; (void)ws_size;
  const float* pos = (const float*)d_in[0];
  const float* w11 = (const float*)d_in[2];
  const float* b11 = (const float*)d_in[3];
  const float* w12 = (const float*)d_in[4];
  const float* b12 = (const float*)d_in[5];
  const float* w21 = (const float*)d_in[6];
  const float* b21 = (const float*)d_in[7];
  const float* w22 = (const float*)d_in[8];
  const float* b22 = (const float*)d_in[9];
  const float* w31 = (const float*)d_in[10];
  const float* b31 = (const float*)d_in[11];
  const float* w32 = (const float*)d_in[12];
  const float* b32 = (const float*)d_in[13];

  float* ws = (float*)d_ws;
  float* p1 = ws; ws += 8 * 2048 * 3;
  float* p2 = ws; ws += 8 * 512 * 3;
  float* p3 = ws; ws += 8 * 512 * 3;
  float* g1 = ws; ws += 8 * 4096 * 32;
  float* x1 = ws; ws += 8 * 2048 * 32;
  float* g2 = ws; ws += 8 * 2048 * 64;
  float* x2 = ws; ws += 8 * 512 * 64;
  float* g3 = ws; ws += 8 * 512 * 128;
  float* x3 = (float*)d_out;

  // layer 1: g1 (tiny, independent), then FPS1 (the long serial chain)
  g_kernel<3, 32><<<dim3(8 * 4096 * 32 / 256), dim3(256), 0, stream>>>(pos, pos, w11, g1, 8 * 4096);
  fps_kernel<4096, 2048, 8><<<dim3(8), dim3(512), 0, stream>>>(pos, p1);

  // fused A: fps2 (p1->p2) overlapped with sa1 (pos,g1,p1 -> x1); SAB = 2048/8 = 256
  fused_kernel<2048, 512, 4, 4096, 32, 32, 8, 256><<<dim3(8 + 8 * 256), dim3(512), 0, stream>>>(
      p1, p2, pos, g1, p1, w12, b11, w11 + 3 * 32, b12, 0.04f, 2048, x1);

  g_kernel<32, 64><<<dim3(8 * 2048 * 64 / 256), dim3(256), 0, stream>>>(x1, p1, w21, g2, 8 * 2048);

  // fused B: fps3 (p2->p3) overlapped with sa2 (p1,g2,p2 -> x2); SAB = 512/8 = 64
  fused_kernel<512, 512, 1, 2048, 64, 64, 8, 64><<<dim3(8 + 8 * 64), dim3(512), 0, stream>>>(
      p2, p3, p1, g2, p2, w22, b21, w21 + 32 * 64, b22, 0.16f, 512, x2);

  g_kernel<64, 128><<<dim3(8 * 512 * 128 / 256), dim3(256), 0, stream>>>(x2, p2, w31, g3, 8 * 512);

  sa_kernel<512, 128, 128, 8><<<dim3(64, 8), dim3(256), 0, stream>>>(
      p2, g3, p3, w32, b31, w31 + 64 * 128, b32, 1.0f, 512, x3);

  tail_kernel<<<dim3(48), dim3(256), 0, stream>>>(p3, (float*)d_out);
}